// Round 17
// baseline (155.911 us; speedup 1.0000x reference)
//
#include <hip/hip_runtime.h>

#define N_NODES 50000
#define N_EDGES 1600000
#define IN_FEATS 128
#define N_HIDDEN 256
#define N_CLASSES 41
#define ECAP 1024
#define NPB 16                 // nodes per block in agg0_mlp (3125 blocks)
#define NBH 64                 // histogram slices
#define EPB 25000              // edges per slice
#define NCONV 128              // converter blocks appended to k1 grid
#define K2B 49                 // k2 blocks (12500 u32 columns / 256)
#define SB 256
#define NB_G1 1563             // ceil(50000/32) gather1 blocks

typedef short  bf16x8 __attribute__((ext_vector_type(8)));
typedef float  f32x4  __attribute__((ext_vector_type(4)));
typedef float  f32x2  __attribute__((ext_vector_type(2)));
typedef unsigned short u16x8 __attribute__((ext_vector_type(8)));

// -------- workspace layout (bytes), 22.7 MB total (< 32.61 MB proven) --------
#define ROWS_OFF  0            // N_NODES+1 int
#define BSUM_OFF  200704       // K2B int
#define HIST_OFF  201728       // [64][50000] u8 (3.2 MB)
#define ESRC_OFF  3401728      // N_EDGES int (6.4 MB)
#define Y1B_OFF   9801728      // [N][64] bf16 (6.4 MB)
#define FEAT8_OFF 16201728     // N_NODES*128 fp8 (6.4 MB)
#define W1P_OFF   22601728     // 64 KB
#define W2P_OFF   22667264     // 24 KB (ends 22,691,840)
// rank8 (N_EDGES u8, 1.6 MB) lives in d_out (dead until gather1_all)

__device__ __forceinline__ unsigned short bf16rne(float x) {
    unsigned b = __float_as_uint(x);
    return (unsigned short)((b + 0x7FFFu + ((b >> 16) & 1u)) >> 16);
}
__device__ __forceinline__ float bf2f(unsigned short u) {
    return __uint_as_float((unsigned)u << 16);
}

// k1: [0,64) LDS histogram + local rank | [64,192) feat->fp8 | 192 pack W1 | 193 pack W2
__global__ __launch_bounds__(512) void k1_hist_conv(
        const int* __restrict__ dst, unsigned char* __restrict__ hist,
        unsigned char* __restrict__ rank8,
        const float* __restrict__ feat, unsigned int* __restrict__ feat8,
        const float* __restrict__ W1, ushort* __restrict__ w1p,
        const float* __restrict__ W2, ushort* __restrict__ w2p) {
    const int b = blockIdx.x, t = threadIdx.x;
    if (b < NBH) {
        __shared__ unsigned int ph[N_NODES / 4];     // 4 x u8 counters per u32, 50 KB
        for (int i = t; i < N_NODES / 4; i += 512) ph[i] = 0;
        __syncthreads();
        const int e1 = b * EPB + EPB;
        for (int e = b * EPB + t; e < e1; e += 512) {
            int d = dst[e];
            unsigned old = atomicAdd(&ph[d >> 2], 1u << ((d & 3) * 8));
            rank8[e] = (unsigned char)((old >> ((d & 3) * 8)) & 0xFFu);
        }
        __syncthreads();
        unsigned int* hrow = (unsigned int*)(hist + (size_t)b * N_NODES);
        for (int i = t; i < N_NODES / 4; i += 512) hrow[i] = ph[i];
    } else if (b < NBH + NCONV) {
        const int cb = b - NBH;
        const int p1 = cb * 12500 + 12500;           // 1.6M float4 quads total
        for (int p = cb * 12500 + t; p < p1; p += 512) {
            float4 v = ((const float4*)feat)[p];
            int wv = 0;
            wv = __builtin_amdgcn_cvt_pk_fp8_f32(v.x, v.y, wv, 0);
            wv = __builtin_amdgcn_cvt_pk_fp8_f32(v.z, v.w, wv, 1);
            feat8[p] = (unsigned int)wv;
        }
    } else if (b == NBH + NCONV) {
        for (int idx = t; idx < 32768; idx += 512) {
            int j = idx & 7, l = (idx >> 3) & 63, ks = (idx >> 9) & 3, nt = idx >> 11;
            int k = ks * 32 + ((l >> 4) * 8) + j;
            int n = nt * 16 + (l & 15);
            w1p[idx] = bf16rne(W1[k * N_HIDDEN + n]);
        }
    } else {
        for (int idx = t; idx < 12288; idx += 512) {
            int j = idx & 7, l = (idx >> 3) & 63, ks = (idx >> 9) & 7, nt = idx >> 12;
            int k = ks * 32 + ((l >> 4) * 8) + j;
            int n = nt * 16 + (l & 15);
            w2p[idx] = (n < N_CLASSES) ? bf16rne(W2[k * N_CLASSES + n]) : (ushort)0;
        }
    }
}

// k2: packed-u32 column scan over 64 slices (thread = 4 nodes) + block scan of totals
__global__ __launch_bounds__(256) void k2_scan(unsigned char* __restrict__ hist,
                                               int* __restrict__ row_start,
                                               int* __restrict__ bsum) {
    __shared__ int sh[256];
    const int t = threadIdx.x;
    const int q = blockIdx.x * 256 + t;
    unsigned int run = 0;
    unsigned int* h32 = (unsigned int*)hist;
    if (q < N_NODES / 4) {
#pragma unroll 8
        for (int b = 0; b < NBH; ++b) {
            unsigned int w = h32[(size_t)b * (N_NODES / 4) + q];
            h32[(size_t)b * (N_NODES / 4) + q] = run;
            run += w;
        }
    }
    const int t0 = run & 0xFF, t1 = (run >> 8) & 0xFF;
    const int t2 = (run >> 16) & 0xFF, t3 = (run >> 24) & 0xFF;
    const int s = t0 + t1 + t2 + t3;
    sh[t] = s;
    __syncthreads();
    for (int off = 1; off < 256; off <<= 1) {
        int x = (t >= off) ? sh[t - off] : 0;
        __syncthreads();
        sh[t] += x;
        __syncthreads();
    }
    const int texc = sh[t] - s;
    if (q < N_NODES / 4) {
        const int n0 = q * 4;
        row_start[n0 + 0] = texc;
        row_start[n0 + 1] = texc + t0;
        row_start[n0 + 2] = texc + t0 + t1;
        row_start[n0 + 3] = texc + t0 + t1 + t2;
    }
    if (t == 255) bsum[blockIdx.x] = sh[255];
}

__global__ __launch_bounds__(256) void scan_b(int* __restrict__ bsum,
                                              int* __restrict__ row_start) {
    __shared__ int sh[256];
    const int t = threadIdx.x;
    int v = (t < K2B) ? bsum[t] : 0;
    sh[t] = v;
    __syncthreads();
    for (int off = 1; off < 256; off <<= 1) {
        int x = (t >= off) ? sh[t - off] : 0;
        __syncthreads();
        sh[t] += x;
        __syncthreads();
    }
    if (t < K2B) bsum[t] = sh[t] - v;
    if (t == K2B - 1) row_start[N_NODES] = sh[t];
}

__global__ __launch_bounds__(SB) void scan_c(const int* __restrict__ bsum,
                                             int* __restrict__ row_start) {
    const int node = blockIdx.x * SB + threadIdx.x;
    if (node < N_NODES) row_start[node] += bsum[node >> 10];
}

// k4: streaming edge placement, no LDS, no atomics
__global__ __launch_bounds__(256) void k4_fill(
        const int* __restrict__ src, const int* __restrict__ dst,
        const unsigned char* __restrict__ rank8, const unsigned char* __restrict__ hist,
        const int* __restrict__ row_start, int* __restrict__ edge_src) {
    const int e = blockIdx.x * 256 + threadIdx.x;
    if (e >= N_EDGES) return;
    const int b = e / EPB;
    const int d = dst[e];
    const int pos = row_start[d] + (int)hist[(size_t)b * N_NODES + d] + (int)rank8[e];
    edge_src[pos] = src[e];
}

// fused: gather 16 nodes (2/wave, fp8 rows 128B, 16 loads in flight/half) -> MFMA MLP
__global__ __launch_bounds__(512) void agg0_mlp(
        const unsigned char* __restrict__ feat8, const int* __restrict__ row_start,
        const int* __restrict__ edge_src,
        const ushort* __restrict__ w1p, const float* __restrict__ b1,
        const ushort* __restrict__ w2p, ushort* __restrict__ y1b) {
    __shared__ ushort xs[NPB][136];
    __shared__ ushort hs[NPB][264];
    const int t = threadIdx.x;
    const int w = t >> 6, lane = t & 63;
    const int half = lane >> 5, l31 = lane & 31;
    const int node0 = blockIdx.x * NPB;

    for (int i = 0; i < 2; ++i) {
        const int nl = w * 2 + i;
        const int node = node0 + nl;
        const int start = row_start[node];
        const int deg = row_start[node + 1] - start;
        float4 acc = make_float4(0.f, 0.f, 0.f, 0.f);
        for (int base = 0; base < deg; base += 64) {
            int cnt = deg - base; if (cnt > 64) cnt = 64;
            int myIdx = 0;
            if (lane < cnt) myIdx = edge_src[start + base + lane];
            for (int j = 0; j < cnt; j += 32) {
#pragma unroll
                for (int u = 0; u < 16; ++u) {
                    int e = j + 2 * u + half;
                    int sn = __shfl(myIdx, e);
                    if (e < cnt) {
                        unsigned int wv = ((const unsigned int*)(feat8 + ((size_t)sn << 7)))[l31];
                        f32x2 lo = __builtin_amdgcn_cvt_pk_f32_fp8(wv, 0);
                        f32x2 hi = __builtin_amdgcn_cvt_pk_f32_fp8(wv, 1);
                        acc.x += lo.x; acc.y += lo.y;
                        acc.z += hi.x; acc.w += hi.y;
                    }
                }
            }
        }
        acc.x += __shfl_xor(acc.x, 32);
        acc.y += __shfl_xor(acc.y, 32);
        acc.z += __shfl_xor(acc.z, 32);
        acc.w += __shfl_xor(acc.w, 32);
        if (half == 0) {
            float invd = 1.0f / fmaxf((float)deg, 1.0f);
            ushort4 sv;
            sv.x = bf16rne(acc.x * invd); sv.y = bf16rne(acc.y * invd);
            sv.z = bf16rne(acc.z * invd); sv.w = bf16rne(acc.w * invd);
            *(ushort4*)&xs[nl][l31 * 4] = sv;
        }
    }
    __syncthreads();

    bf16x8 afr[4];
#pragma unroll
    for (int ks = 0; ks < 4; ++ks)
        afr[ks] = *(const bf16x8*)&xs[lane & 15][ks * 32 + ((lane >> 4) * 8)];

    f32x4 c1[2] = {{0.f, 0.f, 0.f, 0.f}, {0.f, 0.f, 0.f, 0.f}};
#pragma unroll
    for (int nt = 0; nt < 2; ++nt) {
#pragma unroll
        for (int ks = 0; ks < 4; ++ks) {
            bf16x8 bfr = *(const bf16x8*)(w1p + (((w * 2 + nt) * 4 + ks) * 64 + lane) * 8);
            c1[nt] = __builtin_amdgcn_mfma_f32_16x16x32_bf16(afr[ks], bfr, c1[nt], 0, 0, 0);
        }
    }
#pragma unroll
    for (int nt = 0; nt < 2; ++nt) {
        float bb = b1[(w * 2 + nt) * 16 + (lane & 15)];
#pragma unroll
        for (int r = 0; r < 4; ++r) {
            float hv = fmaxf(c1[nt][r] + bb, 0.f);
            hs[(lane >> 4) * 4 + r][(w * 2 + nt) * 16 + (lane & 15)] = bf16rne(hv);
        }
    }
    __syncthreads();

    // GEMM2: waves 0..2 cover classes 16w..16w+15 (41..47 zeros via w2p pad)
    if (w < 3) {
        f32x4 c2 = {0.f, 0.f, 0.f, 0.f};
#pragma unroll
        for (int ks = 0; ks < 8; ++ks) {
            bf16x8 a2 = *(const bf16x8*)&hs[lane & 15][ks * 32 + ((lane >> 4) * 8)];
            bf16x8 b2f = *(const bf16x8*)(w2p + ((w * 8 + ks) * 64 + lane) * 8);
            c2 = __builtin_amdgcn_mfma_f32_16x16x32_bf16(a2, b2f, c2, 0, 0, 0);
        }
#pragma unroll
        for (int r = 0; r < 4; ++r) {
            int node = node0 + (lane >> 4) * 4 + r;
            y1b[(size_t)node * 64 + w * 16 + (lane & 15)] = bf16rne(c2[r]);
        }
    } else if (w == 3) {
#pragma unroll
        for (int r = 0; r < 4; ++r) {
            int node = node0 + (lane >> 4) * 4 + r;
            y1b[(size_t)node * 64 + 48 + (lane & 15)] = 0;
        }
    }
}

// second aggregation over y1b bf16 [N][64] rows; 8-deep unroll; /deg + b2 epilogue
__global__ __launch_bounds__(256) void gather1_all(
        const ushort* __restrict__ y1b,
        const int* __restrict__ row_start, const int* __restrict__ edge_src,
        const float* __restrict__ b2, float* __restrict__ out) {
    __shared__ int eidx[4][ECAP];
    const int t = threadIdx.x;
    const int w = t >> 6, lane = t & 63;
    const int g = lane >> 3, l8 = lane & 7;
    const int n0w = blockIdx.x * 32 + w * 8;

    int v = row_start[min(n0w + lane, N_NODES)];
    const int gbase = __shfl(v, 0);
    const int sg = __shfl(v, g);
    const int cnt = __shfl(v, g + 1) - sg;
    const int sl = sg - gbase;
    const int tot = __shfl(v, 8) - gbase;

    for (int i = lane; i < min(tot, ECAP); i += 64)
        eidx[w][i] = edge_src[gbase + i];
    __syncthreads();

    int maxc = cnt;
    maxc = max(maxc, __shfl_xor(maxc, 32));
    maxc = max(maxc, __shfl_xor(maxc, 16));
    maxc = max(maxc, __shfl_xor(maxc, 8));

    const ushort* fp = y1b + l8 * 8;
    float s0 = 0.f, s1 = 0.f, s2 = 0.f, s3 = 0.f;
    float s4 = 0.f, s5 = 0.f, s6 = 0.f, s7 = 0.f;
    for (int k = 0; k < maxc; k += 8) {
        u16x8 vv[8];
        int nv = 0;
#pragma unroll
        for (int u = 0; u < 8; ++u) {
            int e = k + u;
            if (e < cnt) {
                int p = sl + e;
                int idx = (p < ECAP) ? eidx[w][p] : edge_src[gbase + p];
                vv[u] = *(const u16x8*)(fp + (size_t)idx * 64);
                nv = u + 1;
            }
        }
#pragma unroll
        for (int u = 0; u < 8; ++u) {
            if (u < nv) {
                s0 += bf2f(vv[u][0]); s1 += bf2f(vv[u][1]);
                s2 += bf2f(vv[u][2]); s3 += bf2f(vv[u][3]);
                s4 += bf2f(vv[u][4]); s5 += bf2f(vv[u][5]);
                s6 += bf2f(vv[u][6]); s7 += bf2f(vv[u][7]);
            }
        }
    }
    const int node = n0w + g;
    if (node < N_NODES) {
        float invd = 1.0f / fmaxf((float)cnt, 1.0f);
        float sv[8] = {s0, s1, s2, s3, s4, s5, s6, s7};
        const int c0 = l8 * 8;
#pragma unroll
        for (int j = 0; j < 8; ++j) {
            int c = c0 + j;
            if (c < N_CLASSES)
                out[(size_t)node * N_CLASSES + c] = sv[j] * invd + b2[c];
        }
    }
}

extern "C" void kernel_launch(void* const* d_in, const int* in_sizes, int n_in,
                              void* d_out, int out_size, void* d_ws, size_t ws_size,
                              hipStream_t stream) {
    const float* feat = (const float*)d_in[0];
    const int*   src  = (const int*)d_in[1];
    const int*   dst  = (const int*)d_in[2];
    const float* W1   = (const float*)d_in[3];
    const float* b1   = (const float*)d_in[4];
    const float* W2   = (const float*)d_in[5];
    const float* b2   = (const float*)d_in[6];
    float* out = (float*)d_out;

    char* ws = (char*)d_ws;
    int*           row_start = (int*)(ws + ROWS_OFF);
    int*           bsum      = (int*)(ws + BSUM_OFF);
    unsigned char* hist      = (unsigned char*)(ws + HIST_OFF);
    int*           edge_src  = (int*)(ws + ESRC_OFF);
    ushort*        y1b       = (ushort*)(ws + Y1B_OFF);
    unsigned char* feat8     = (unsigned char*)(ws + FEAT8_OFF);
    ushort*        w1p       = (ushort*)(ws + W1P_OFF);
    ushort*        w2p       = (ushort*)(ws + W2P_OFF);
    unsigned char* rank8     = (unsigned char*)d_out;   // 1.6 MB scratch in d_out

    k1_hist_conv<<<NBH + NCONV + 2, 512, 0, stream>>>(dst, hist, rank8, feat,
                                                      (unsigned int*)feat8,
                                                      W1, w1p, W2, w2p);
    k2_scan<<<K2B, 256, 0, stream>>>(hist, row_start, bsum);
    scan_b<<<1, 256, 0, stream>>>(bsum, row_start);
    scan_c<<<(N_NODES + SB - 1) / SB, SB, 0, stream>>>(bsum, row_start);
    k4_fill<<<(N_EDGES + 255) / 256, 256, 0, stream>>>(src, dst, rank8, hist,
                                                       row_start, edge_src);

    agg0_mlp<<<N_NODES / NPB, 512, 0, stream>>>(feat8, row_start, edge_src,
                                                w1p, b1, w2p, y1b);

    gather1_all<<<NB_G1, 256, 0, stream>>>(y1b, row_start, edge_src, b2, out);
}

// Round 18
// 125.611 us; speedup vs baseline: 1.2412x; 1.2412x over previous
//
#include <hip/hip_runtime.h>

#define N_NODES 50000
#define N_EDGES 1600000
#define IN_FEATS 128
#define N_HIDDEN 256
#define N_CLASSES 41
#define ECAP 1024
#define NPB 16                 // nodes per block in agg0_mlp (3125 blocks)
#define NBH 64                 // histogram slices
#define EPB 25000              // edges per slice
#define NCONV 128              // converter blocks appended to k1 grid
#define K2B 49                 // k2 blocks (12500 u32 columns / 256)
#define SB 256
#define NB_G1 1563             // ceil(50000/32) gather1 blocks

typedef short  bf16x8 __attribute__((ext_vector_type(8)));
typedef float  f32x4  __attribute__((ext_vector_type(4)));
typedef float  f32x2  __attribute__((ext_vector_type(2)));
typedef unsigned short u16x8 __attribute__((ext_vector_type(8)));

// -------- workspace layout (bytes), 22.7 MB total (< 32.61 MB proven) --------
#define ROWS_OFF  0            // N_NODES+1 int
#define BSUM_OFF  200704       // K2B int
#define HIST_OFF  201728       // [64][50000] u8 (3.2 MB)
#define ESRC_OFF  3401728      // N_EDGES int (6.4 MB)
#define Y1B_OFF   9801728      // [N][64] bf16 (6.4 MB)
#define FEAT8_OFF 16201728     // N_NODES*128 fp8 (6.4 MB)
#define W1P_OFF   22601728     // 64 KB
#define W2P_OFF   22667264     // 24 KB (ends 22,691,840)
// rank8 (N_EDGES u8, 1.6 MB) lives in d_out (dead until gather1_all)

__device__ __forceinline__ unsigned short bf16rne(float x) {
    unsigned b = __float_as_uint(x);
    return (unsigned short)((b + 0x7FFFu + ((b >> 16) & 1u)) >> 16);
}
__device__ __forceinline__ float bf2f(unsigned short u) {
    return __uint_as_float((unsigned)u << 16);
}

// k1: [0,64) LDS histogram + local rank | [64,192) feat->fp8 | 192 pack W1 | 193 pack W2
__global__ __launch_bounds__(512) void k1_hist_conv(
        const int* __restrict__ dst, unsigned char* __restrict__ hist,
        unsigned char* __restrict__ rank8,
        const float* __restrict__ feat, unsigned int* __restrict__ feat8,
        const float* __restrict__ W1, ushort* __restrict__ w1p,
        const float* __restrict__ W2, ushort* __restrict__ w2p) {
    const int b = blockIdx.x, t = threadIdx.x;
    if (b < NBH) {
        __shared__ unsigned int ph[N_NODES / 4];     // 4 x u8 counters per u32, 50 KB
        for (int i = t; i < N_NODES / 4; i += 512) ph[i] = 0;
        __syncthreads();
        const int e1 = b * EPB + EPB;
        for (int e = b * EPB + t; e < e1; e += 512) {
            int d = dst[e];
            unsigned old = atomicAdd(&ph[d >> 2], 1u << ((d & 3) * 8));
            rank8[e] = (unsigned char)((old >> ((d & 3) * 8)) & 0xFFu);
        }
        __syncthreads();
        unsigned int* hrow = (unsigned int*)(hist + (size_t)b * N_NODES);
        for (int i = t; i < N_NODES / 4; i += 512) hrow[i] = ph[i];
    } else if (b < NBH + NCONV) {
        const int cb = b - NBH;
        const int p1 = cb * 12500 + 12500;           // 1.6M float4 quads total
        for (int p = cb * 12500 + t; p < p1; p += 512) {
            float4 v = ((const float4*)feat)[p];
            int wv = 0;
            wv = __builtin_amdgcn_cvt_pk_fp8_f32(v.x, v.y, wv, 0);
            wv = __builtin_amdgcn_cvt_pk_fp8_f32(v.z, v.w, wv, 1);
            feat8[p] = (unsigned int)wv;
        }
    } else if (b == NBH + NCONV) {
        for (int idx = t; idx < 32768; idx += 512) {
            int j = idx & 7, l = (idx >> 3) & 63, ks = (idx >> 9) & 3, nt = idx >> 11;
            int k = ks * 32 + ((l >> 4) * 8) + j;
            int n = nt * 16 + (l & 15);
            w1p[idx] = bf16rne(W1[k * N_HIDDEN + n]);
        }
    } else {
        for (int idx = t; idx < 12288; idx += 512) {
            int j = idx & 7, l = (idx >> 3) & 63, ks = (idx >> 9) & 7, nt = idx >> 12;
            int k = ks * 32 + ((l >> 4) * 8) + j;
            int n = nt * 16 + (l & 15);
            w2p[idx] = (n < N_CLASSES) ? bf16rne(W2[k * N_CLASSES + n]) : (ushort)0;
        }
    }
}

// k2: packed-u32 column scan over 64 slices (thread = 4 nodes) + block scan of totals
__global__ __launch_bounds__(256) void k2_scan(unsigned char* __restrict__ hist,
                                               int* __restrict__ row_start,
                                               int* __restrict__ bsum) {
    __shared__ int sh[256];
    const int t = threadIdx.x;
    const int q = blockIdx.x * 256 + t;
    unsigned int run = 0;
    unsigned int* h32 = (unsigned int*)hist;
    if (q < N_NODES / 4) {
#pragma unroll 8
        for (int b = 0; b < NBH; ++b) {
            unsigned int w = h32[(size_t)b * (N_NODES / 4) + q];
            h32[(size_t)b * (N_NODES / 4) + q] = run;
            run += w;
        }
    }
    const int t0 = run & 0xFF, t1 = (run >> 8) & 0xFF;
    const int t2 = (run >> 16) & 0xFF, t3 = (run >> 24) & 0xFF;
    const int s = t0 + t1 + t2 + t3;
    sh[t] = s;
    __syncthreads();
    for (int off = 1; off < 256; off <<= 1) {
        int x = (t >= off) ? sh[t - off] : 0;
        __syncthreads();
        sh[t] += x;
        __syncthreads();
    }
    const int texc = sh[t] - s;
    if (q < N_NODES / 4) {
        const int n0 = q * 4;
        row_start[n0 + 0] = texc;
        row_start[n0 + 1] = texc + t0;
        row_start[n0 + 2] = texc + t0 + t1;
        row_start[n0 + 3] = texc + t0 + t1 + t2;
    }
    if (t == 255) bsum[blockIdx.x] = sh[255];
}

// scan_c: per-block wave-scan of the 49 block sums + add offsets (scan_b folded in)
__global__ __launch_bounds__(SB) void scan_c(const int* __restrict__ bsum,
                                             int* __restrict__ row_start) {
    __shared__ int pre[64];
    const int t = threadIdx.x;
    if (t < 64) {
        int v = (t < K2B) ? bsum[t] : 0;
#pragma unroll
        for (int off = 1; off < 64; off <<= 1) {
            int x = __shfl_up(v, off);
            if (t >= off) v += x;
        }
        pre[t] = v;                                  // inclusive prefix
    }
    __syncthreads();
    const int node = blockIdx.x * SB + t;
    if (node < N_NODES) {
        int blk = node >> 10;
        row_start[node] += (blk == 0) ? 0 : pre[blk - 1];
    }
    if (blockIdx.x == 0 && t == 0) row_start[N_NODES] = N_EDGES;
}

// k4: streaming edge placement, no LDS, no atomics
__global__ __launch_bounds__(256) void k4_fill(
        const int* __restrict__ src, const int* __restrict__ dst,
        const unsigned char* __restrict__ rank8, const unsigned char* __restrict__ hist,
        const int* __restrict__ row_start, int* __restrict__ edge_src) {
    const int e = blockIdx.x * 256 + threadIdx.x;
    if (e >= N_EDGES) return;
    const int b = e / EPB;
    const int d = dst[e];
    const int pos = row_start[d] + (int)hist[(size_t)b * N_NODES + d] + (int)rank8[e];
    edge_src[pos] = src[e];
}

// fused: gather 16 nodes (2/wave, fp8 rows 128B) -> MFMA MLP
// gather uses explicit 16-deep load array to force in-flight loads (VGPR-backed)
__global__ __launch_bounds__(512) void agg0_mlp(
        const unsigned char* __restrict__ feat8, const int* __restrict__ row_start,
        const int* __restrict__ edge_src,
        const ushort* __restrict__ w1p, const float* __restrict__ b1,
        const ushort* __restrict__ w2p, ushort* __restrict__ y1b) {
    __shared__ ushort xs[NPB][136];
    __shared__ ushort hs[NPB][264];
    const int t = threadIdx.x;
    const int w = t >> 6, lane = t & 63;
    const int half = lane >> 5, l31 = lane & 31;
    const int node0 = blockIdx.x * NPB;

    for (int i = 0; i < 2; ++i) {
        const int nl = w * 2 + i;
        const int node = node0 + nl;
        const int start = row_start[node];
        const int deg = row_start[node + 1] - start;
        float4 acc = make_float4(0.f, 0.f, 0.f, 0.f);
        for (int base = 0; base < deg; base += 64) {
            int cnt = deg - base; if (cnt > 64) cnt = 64;
            int myIdx = 0;
            if (lane < cnt) myIdx = edge_src[start + base + lane];
            for (int j = 0; j < cnt; j += 32) {
                unsigned int lv[16];
                int nv = 0;
#pragma unroll
                for (int u = 0; u < 16; ++u) {
                    int e = j + 2 * u + half;
                    int sn = __shfl(myIdx, e);
                    if (e < cnt) {
                        lv[u] = ((const unsigned int*)(feat8 + ((size_t)sn << 7)))[l31];
                        nv = u + 1;
                    }
                }
#pragma unroll
                for (int u = 0; u < 16; ++u) {
                    if (u < nv) {
                        f32x2 lo = __builtin_amdgcn_cvt_pk_f32_fp8(lv[u], 0);
                        f32x2 hi = __builtin_amdgcn_cvt_pk_f32_fp8(lv[u], 1);
                        acc.x += lo.x; acc.y += lo.y;
                        acc.z += hi.x; acc.w += hi.y;
                    }
                }
            }
        }
        acc.x += __shfl_xor(acc.x, 32);
        acc.y += __shfl_xor(acc.y, 32);
        acc.z += __shfl_xor(acc.z, 32);
        acc.w += __shfl_xor(acc.w, 32);
        if (half == 0) {
            float invd = 1.0f / fmaxf((float)deg, 1.0f);
            ushort4 sv;
            sv.x = bf16rne(acc.x * invd); sv.y = bf16rne(acc.y * invd);
            sv.z = bf16rne(acc.z * invd); sv.w = bf16rne(acc.w * invd);
            *(ushort4*)&xs[nl][l31 * 4] = sv;
        }
    }
    __syncthreads();

    bf16x8 afr[4];
#pragma unroll
    for (int ks = 0; ks < 4; ++ks)
        afr[ks] = *(const bf16x8*)&xs[lane & 15][ks * 32 + ((lane >> 4) * 8)];

    f32x4 c1[2] = {{0.f, 0.f, 0.f, 0.f}, {0.f, 0.f, 0.f, 0.f}};
#pragma unroll
    for (int nt = 0; nt < 2; ++nt) {
#pragma unroll
        for (int ks = 0; ks < 4; ++ks) {
            bf16x8 bfr = *(const bf16x8*)(w1p + (((w * 2 + nt) * 4 + ks) * 64 + lane) * 8);
            c1[nt] = __builtin_amdgcn_mfma_f32_16x16x32_bf16(afr[ks], bfr, c1[nt], 0, 0, 0);
        }
    }
#pragma unroll
    for (int nt = 0; nt < 2; ++nt) {
        float bb = b1[(w * 2 + nt) * 16 + (lane & 15)];
#pragma unroll
        for (int r = 0; r < 4; ++r) {
            float hv = fmaxf(c1[nt][r] + bb, 0.f);
            hs[(lane >> 4) * 4 + r][(w * 2 + nt) * 16 + (lane & 15)] = bf16rne(hv);
        }
    }
    __syncthreads();

    // GEMM2: waves 0..2 cover classes 16w..16w+15 (41..47 zeros via w2p pad)
    if (w < 3) {
        f32x4 c2 = {0.f, 0.f, 0.f, 0.f};
#pragma unroll
        for (int ks = 0; ks < 8; ++ks) {
            bf16x8 a2 = *(const bf16x8*)&hs[lane & 15][ks * 32 + ((lane >> 4) * 8)];
            bf16x8 b2f = *(const bf16x8*)(w2p + ((w * 8 + ks) * 64 + lane) * 8);
            c2 = __builtin_amdgcn_mfma_f32_16x16x32_bf16(a2, b2f, c2, 0, 0, 0);
        }
#pragma unroll
        for (int r = 0; r < 4; ++r) {
            int node = node0 + (lane >> 4) * 4 + r;
            y1b[(size_t)node * 64 + w * 16 + (lane & 15)] = bf16rne(c2[r]);
        }
    } else if (w == 3) {
#pragma unroll
        for (int r = 0; r < 4; ++r) {
            int node = node0 + (lane >> 4) * 4 + r;
            y1b[(size_t)node * 64 + 48 + (lane & 15)] = 0;
        }
    }
}

// second aggregation over y1b bf16 [N][64] rows; 8-deep array unroll
__global__ __launch_bounds__(256) void gather1_all(
        const ushort* __restrict__ y1b,
        const int* __restrict__ row_start, const int* __restrict__ edge_src,
        const float* __restrict__ b2, float* __restrict__ out) {
    __shared__ int eidx[4][ECAP];
    const int t = threadIdx.x;
    const int w = t >> 6, lane = t & 63;
    const int g = lane >> 3, l8 = lane & 7;
    const int n0w = blockIdx.x * 32 + w * 8;

    int v = row_start[min(n0w + lane, N_NODES)];
    const int gbase = __shfl(v, 0);
    const int sg = __shfl(v, g);
    const int cnt = __shfl(v, g + 1) - sg;
    const int sl = sg - gbase;
    const int tot = __shfl(v, 8) - gbase;

    for (int i = lane; i < min(tot, ECAP); i += 64)
        eidx[w][i] = edge_src[gbase + i];
    __syncthreads();

    int maxc = cnt;
    maxc = max(maxc, __shfl_xor(maxc, 32));
    maxc = max(maxc, __shfl_xor(maxc, 16));
    maxc = max(maxc, __shfl_xor(maxc, 8));

    const ushort* fp = y1b + l8 * 8;
    float s0 = 0.f, s1 = 0.f, s2 = 0.f, s3 = 0.f;
    float s4 = 0.f, s5 = 0.f, s6 = 0.f, s7 = 0.f;
    for (int k = 0; k < maxc; k += 8) {
        u16x8 vv[8];
        int nv = 0;
#pragma unroll
        for (int u = 0; u < 8; ++u) {
            int e = k + u;
            if (e < cnt) {
                int p = sl + e;
                int idx = (p < ECAP) ? eidx[w][p] : edge_src[gbase + p];
                vv[u] = *(const u16x8*)(fp + (size_t)idx * 64);
                nv = u + 1;
            }
        }
#pragma unroll
        for (int u = 0; u < 8; ++u) {
            if (u < nv) {
                s0 += bf2f(vv[u][0]); s1 += bf2f(vv[u][1]);
                s2 += bf2f(vv[u][2]); s3 += bf2f(vv[u][3]);
                s4 += bf2f(vv[u][4]); s5 += bf2f(vv[u][5]);
                s6 += bf2f(vv[u][6]); s7 += bf2f(vv[u][7]);
            }
        }
    }
    const int node = n0w + g;
    if (node < N_NODES) {
        float invd = 1.0f / fmaxf((float)cnt, 1.0f);
        float sv[8] = {s0, s1, s2, s3, s4, s5, s6, s7};
        const int c0 = l8 * 8;
#pragma unroll
        for (int j = 0; j < 8; ++j) {
            int c = c0 + j;
            if (c < N_CLASSES)
                out[(size_t)node * N_CLASSES + c] = sv[j] * invd + b2[c];
        }
    }
}

extern "C" void kernel_launch(void* const* d_in, const int* in_sizes, int n_in,
                              void* d_out, int out_size, void* d_ws, size_t ws_size,
                              hipStream_t stream) {
    const float* feat = (const float*)d_in[0];
    const int*   src  = (const int*)d_in[1];
    const int*   dst  = (const int*)d_in[2];
    const float* W1   = (const float*)d_in[3];
    const float* b1   = (const float*)d_in[4];
    const float* W2   = (const float*)d_in[5];
    const float* b2   = (const float*)d_in[6];
    float* out = (float*)d_out;

    char* ws = (char*)d_ws;
    int*           row_start = (int*)(ws + ROWS_OFF);
    int*           bsum      = (int*)(ws + BSUM_OFF);
    unsigned char* hist      = (unsigned char*)(ws + HIST_OFF);
    int*           edge_src  = (int*)(ws + ESRC_OFF);
    ushort*        y1b       = (ushort*)(ws + Y1B_OFF);
    unsigned char* feat8     = (unsigned char*)(ws + FEAT8_OFF);
    ushort*        w1p       = (ushort*)(ws + W1P_OFF);
    ushort*        w2p       = (ushort*)(ws + W2P_OFF);
    unsigned char* rank8     = (unsigned char*)d_out;   // 1.6 MB scratch in d_out

    k1_hist_conv<<<NBH + NCONV + 2, 512, 0, stream>>>(dst, hist, rank8, feat,
                                                      (unsigned int*)feat8,
                                                      W1, w1p, W2, w2p);
    k2_scan<<<K2B, 256, 0, stream>>>(hist, row_start, bsum);
    scan_c<<<(N_NODES + SB - 1) / SB, SB, 0, stream>>>(bsum, row_start);
    k4_fill<<<(N_EDGES + 255) / 256, 256, 0, stream>>>(src, dst, rank8, hist,
                                                       row_start, edge_src);

    agg0_mlp<<<N_NODES / NPB, 512, 0, stream>>>(feat8, row_start, edge_src,
                                                w1p, b1, w2p, y1b);

    gather1_all<<<NB_G1, 256, 0, stream>>>(y1b, row_start, edge_src, b2, out);
}

// Round 19
// 125.600 us; speedup vs baseline: 1.2413x; 1.0001x over previous
//
#include <hip/hip_runtime.h>

#define N_NODES 50000
#define N_EDGES 1600000
#define IN_FEATS 128
#define N_HIDDEN 256
#define N_CLASSES 41
#define ECAP 1024
#define NPB 16                 // nodes per block in agg0_mlp (3125 blocks)
#define NBH 64                 // histogram slices
#define EPB 25000              // edges per slice
#define NCONV 128              // converter blocks appended to k1 grid
#define K2B 49                 // k2 blocks (12500 u32 columns / 256)
#define SB 256
#define NB_G1 1563             // ceil(50000/32) gather1 blocks

typedef short  bf16x8 __attribute__((ext_vector_type(8)));
typedef float  f32x4  __attribute__((ext_vector_type(4)));
typedef float  f32x2  __attribute__((ext_vector_type(2)));
typedef unsigned short u16x8 __attribute__((ext_vector_type(8)));

// -------- workspace layout (bytes), 19.5 MB total (< 32.61 MB proven) --------
#define ROWS_OFF  0            // N_NODES+1 int
#define BSUM_OFF  200704       // K2B int
#define HIST_OFF  201728       // [64][50000] u8 (3.2 MB)
#define ESRC_OFF  3401728      // N_EDGES u16 (3.2 MB)
#define Y1B_OFF   6601728      // [N][64] bf16 (6.4 MB)
#define FEAT8_OFF 13001728     // N_NODES*128 fp8 (6.4 MB)
#define W1P_OFF   19401728     // 64 KB
#define W2P_OFF   19467264     // 24 KB (ends 19,491,840)
// rank8 (N_EDGES u8, 1.6 MB) lives in d_out (dead until gather1_all)

__device__ __forceinline__ unsigned short bf16rne(float x) {
    unsigned b = __float_as_uint(x);
    return (unsigned short)((b + 0x7FFFu + ((b >> 16) & 1u)) >> 16);
}
__device__ __forceinline__ float bf2f(unsigned short u) {
    return __uint_as_float((unsigned)u << 16);
}

// k1: [0,64) LDS histogram + local rank | [64,192) feat->fp8 | 192 pack W1 | 193 pack W2
__global__ __launch_bounds__(512) void k1_hist_conv(
        const int* __restrict__ dst, unsigned char* __restrict__ hist,
        unsigned char* __restrict__ rank8,
        const float* __restrict__ feat, unsigned int* __restrict__ feat8,
        const float* __restrict__ W1, ushort* __restrict__ w1p,
        const float* __restrict__ W2, ushort* __restrict__ w2p) {
    const int b = blockIdx.x, t = threadIdx.x;
    if (b < NBH) {
        __shared__ unsigned int ph[N_NODES / 4];     // 4 x u8 counters per u32, 50 KB
        for (int i = t; i < N_NODES / 4; i += 512) ph[i] = 0;
        __syncthreads();
        const int e1 = b * EPB + EPB;
        for (int e = b * EPB + t; e < e1; e += 512) {
            int d = dst[e];
            unsigned old = atomicAdd(&ph[d >> 2], 1u << ((d & 3) * 8));
            rank8[e] = (unsigned char)((old >> ((d & 3) * 8)) & 0xFFu);
        }
        __syncthreads();
        unsigned int* hrow = (unsigned int*)(hist + (size_t)b * N_NODES);
        for (int i = t; i < N_NODES / 4; i += 512) hrow[i] = ph[i];
    } else if (b < NBH + NCONV) {
        const int cb = b - NBH;
        const int p1 = cb * 12500 + 12500;           // 1.6M float4 quads total
        for (int p = cb * 12500 + t; p < p1; p += 512) {
            float4 v = ((const float4*)feat)[p];
            int wv = 0;
            wv = __builtin_amdgcn_cvt_pk_fp8_f32(v.x, v.y, wv, 0);
            wv = __builtin_amdgcn_cvt_pk_fp8_f32(v.z, v.w, wv, 1);
            feat8[p] = (unsigned int)wv;
        }
    } else if (b == NBH + NCONV) {
        for (int idx = t; idx < 32768; idx += 512) {
            int j = idx & 7, l = (idx >> 3) & 63, ks = (idx >> 9) & 3, nt = idx >> 11;
            int k = ks * 32 + ((l >> 4) * 8) + j;
            int n = nt * 16 + (l & 15);
            w1p[idx] = bf16rne(W1[k * N_HIDDEN + n]);
        }
    } else {
        for (int idx = t; idx < 12288; idx += 512) {
            int j = idx & 7, l = (idx >> 3) & 63, ks = (idx >> 9) & 7, nt = idx >> 12;
            int k = ks * 32 + ((l >> 4) * 8) + j;
            int n = nt * 16 + (l & 15);
            w2p[idx] = (n < N_CLASSES) ? bf16rne(W2[k * N_CLASSES + n]) : (ushort)0;
        }
    }
}

// k2: packed-u32 column scan over 64 slices (thread = 4 nodes) + block scan of totals
__global__ __launch_bounds__(256) void k2_scan(unsigned char* __restrict__ hist,
                                               int* __restrict__ row_start,
                                               int* __restrict__ bsum) {
    __shared__ int sh[256];
    const int t = threadIdx.x;
    const int q = blockIdx.x * 256 + t;
    unsigned int run = 0;
    unsigned int* h32 = (unsigned int*)hist;
    if (q < N_NODES / 4) {
#pragma unroll 8
        for (int b = 0; b < NBH; ++b) {
            unsigned int w = h32[(size_t)b * (N_NODES / 4) + q];
            h32[(size_t)b * (N_NODES / 4) + q] = run;
            run += w;
        }
    }
    const int t0 = run & 0xFF, t1 = (run >> 8) & 0xFF;
    const int t2 = (run >> 16) & 0xFF, t3 = (run >> 24) & 0xFF;
    const int s = t0 + t1 + t2 + t3;
    sh[t] = s;
    __syncthreads();
    for (int off = 1; off < 256; off <<= 1) {
        int x = (t >= off) ? sh[t - off] : 0;
        __syncthreads();
        sh[t] += x;
        __syncthreads();
    }
    const int texc = sh[t] - s;
    if (q < N_NODES / 4) {
        const int n0 = q * 4;
        row_start[n0 + 0] = texc;
        row_start[n0 + 1] = texc + t0;
        row_start[n0 + 2] = texc + t0 + t1;
        row_start[n0 + 3] = texc + t0 + t1 + t2;
    }
    if (t == 255) bsum[blockIdx.x] = sh[255];
}

// scan_c: per-block wave-scan of the 49 block sums + add offsets
__global__ __launch_bounds__(SB) void scan_c(const int* __restrict__ bsum,
                                             int* __restrict__ row_start) {
    __shared__ int pre[64];
    const int t = threadIdx.x;
    if (t < 64) {
        int v = (t < K2B) ? bsum[t] : 0;
#pragma unroll
        for (int off = 1; off < 64; off <<= 1) {
            int x = __shfl_up(v, off);
            if (t >= off) v += x;
        }
        pre[t] = v;                                  // inclusive prefix
    }
    __syncthreads();
    const int node = blockIdx.x * SB + t;
    if (node < N_NODES) {
        int blk = node >> 10;
        row_start[node] += (blk == 0) ? 0 : pre[blk - 1];
    }
    if (blockIdx.x == 0 && t == 0) row_start[N_NODES] = N_EDGES;
}

// k4: streaming edge placement into u16 edge list (3.2 MB, XCD-L2-resident)
__global__ __launch_bounds__(256) void k4_fill(
        const int* __restrict__ src, const int* __restrict__ dst,
        const unsigned char* __restrict__ rank8, const unsigned char* __restrict__ hist,
        const int* __restrict__ row_start, ushort* __restrict__ edge_src) {
    const int e = blockIdx.x * 256 + threadIdx.x;
    if (e >= N_EDGES) return;
    const int b = e / EPB;
    const int d = dst[e];
    const int pos = row_start[d] + (int)hist[(size_t)b * N_NODES + d] + (int)rank8[e];
    edge_src[pos] = (ushort)src[e];
}

// fused: gather 16 nodes (2/wave, fp8 rows 128B) -> MFMA MLP
// gather uses explicit 16-deep load array to force in-flight loads (VGPR-backed)
__global__ __launch_bounds__(512) void agg0_mlp(
        const unsigned char* __restrict__ feat8, const int* __restrict__ row_start,
        const ushort* __restrict__ edge_src,
        const ushort* __restrict__ w1p, const float* __restrict__ b1,
        const ushort* __restrict__ w2p, ushort* __restrict__ y1b) {
    __shared__ ushort xs[NPB][136];
    __shared__ ushort hs[NPB][264];
    const int t = threadIdx.x;
    const int w = t >> 6, lane = t & 63;
    const int half = lane >> 5, l31 = lane & 31;
    const int node0 = blockIdx.x * NPB;

    for (int i = 0; i < 2; ++i) {
        const int nl = w * 2 + i;
        const int node = node0 + nl;
        const int start = row_start[node];
        const int deg = row_start[node + 1] - start;
        float4 acc = make_float4(0.f, 0.f, 0.f, 0.f);
        for (int base = 0; base < deg; base += 64) {
            int cnt = deg - base; if (cnt > 64) cnt = 64;
            int myIdx = 0;
            if (lane < cnt) myIdx = (int)edge_src[start + base + lane];
            for (int j = 0; j < cnt; j += 32) {
                unsigned int lv[16];
                int nv = 0;
#pragma unroll
                for (int u = 0; u < 16; ++u) {
                    int e = j + 2 * u + half;
                    int sn = __shfl(myIdx, e);
                    if (e < cnt) {
                        lv[u] = ((const unsigned int*)(feat8 + ((size_t)sn << 7)))[l31];
                        nv = u + 1;
                    }
                }
#pragma unroll
                for (int u = 0; u < 16; ++u) {
                    if (u < nv) {
                        f32x2 lo = __builtin_amdgcn_cvt_pk_f32_fp8(lv[u], 0);
                        f32x2 hi = __builtin_amdgcn_cvt_pk_f32_fp8(lv[u], 1);
                        acc.x += lo.x; acc.y += lo.y;
                        acc.z += hi.x; acc.w += hi.y;
                    }
                }
            }
        }
        acc.x += __shfl_xor(acc.x, 32);
        acc.y += __shfl_xor(acc.y, 32);
        acc.z += __shfl_xor(acc.z, 32);
        acc.w += __shfl_xor(acc.w, 32);
        if (half == 0) {
            float invd = 1.0f / fmaxf((float)deg, 1.0f);
            ushort4 sv;
            sv.x = bf16rne(acc.x * invd); sv.y = bf16rne(acc.y * invd);
            sv.z = bf16rne(acc.z * invd); sv.w = bf16rne(acc.w * invd);
            *(ushort4*)&xs[nl][l31 * 4] = sv;
        }
    }
    __syncthreads();

    bf16x8 afr[4];
#pragma unroll
    for (int ks = 0; ks < 4; ++ks)
        afr[ks] = *(const bf16x8*)&xs[lane & 15][ks * 32 + ((lane >> 4) * 8)];

    f32x4 c1[2] = {{0.f, 0.f, 0.f, 0.f}, {0.f, 0.f, 0.f, 0.f}};
#pragma unroll
    for (int nt = 0; nt < 2; ++nt) {
#pragma unroll
        for (int ks = 0; ks < 4; ++ks) {
            bf16x8 bfr = *(const bf16x8*)(w1p + (((w * 2 + nt) * 4 + ks) * 64 + lane) * 8);
            c1[nt] = __builtin_amdgcn_mfma_f32_16x16x32_bf16(afr[ks], bfr, c1[nt], 0, 0, 0);
        }
    }
#pragma unroll
    for (int nt = 0; nt < 2; ++nt) {
        float bb = b1[(w * 2 + nt) * 16 + (lane & 15)];
#pragma unroll
        for (int r = 0; r < 4; ++r) {
            float hv = fmaxf(c1[nt][r] + bb, 0.f);
            hs[(lane >> 4) * 4 + r][(w * 2 + nt) * 16 + (lane & 15)] = bf16rne(hv);
        }
    }
    __syncthreads();

    // GEMM2: waves 0..2 cover classes 16w..16w+15 (41..47 zeros via w2p pad)
    if (w < 3) {
        f32x4 c2 = {0.f, 0.f, 0.f, 0.f};
#pragma unroll
        for (int ks = 0; ks < 8; ++ks) {
            bf16x8 a2 = *(const bf16x8*)&hs[lane & 15][ks * 32 + ((lane >> 4) * 8)];
            bf16x8 b2f = *(const bf16x8*)(w2p + ((w * 8 + ks) * 64 + lane) * 8);
            c2 = __builtin_amdgcn_mfma_f32_16x16x32_bf16(a2, b2f, c2, 0, 0, 0);
        }
#pragma unroll
        for (int r = 0; r < 4; ++r) {
            int node = node0 + (lane >> 4) * 4 + r;
            y1b[(size_t)node * 64 + w * 16 + (lane & 15)] = bf16rne(c2[r]);
        }
    } else if (w == 3) {
#pragma unroll
        for (int r = 0; r < 4; ++r) {
            int node = node0 + (lane >> 4) * 4 + r;
            y1b[(size_t)node * 64 + 48 + (lane & 15)] = 0;
        }
    }
}

// second aggregation over y1b bf16 [N][64] rows; 8-deep array unroll
__global__ __launch_bounds__(256) void gather1_all(
        const ushort* __restrict__ y1b,
        const int* __restrict__ row_start, const ushort* __restrict__ edge_src,
        const float* __restrict__ b2, float* __restrict__ out) {
    __shared__ ushort eidx[4][ECAP];
    const int t = threadIdx.x;
    const int w = t >> 6, lane = t & 63;
    const int g = lane >> 3, l8 = lane & 7;
    const int n0w = blockIdx.x * 32 + w * 8;

    int v = row_start[min(n0w + lane, N_NODES)];
    const int gbase = __shfl(v, 0);
    const int sg = __shfl(v, g);
    const int cnt = __shfl(v, g + 1) - sg;
    const int sl = sg - gbase;
    const int tot = __shfl(v, 8) - gbase;

    for (int i = lane; i < min(tot, ECAP); i += 64)
        eidx[w][i] = edge_src[gbase + i];
    __syncthreads();

    int maxc = cnt;
    maxc = max(maxc, __shfl_xor(maxc, 32));
    maxc = max(maxc, __shfl_xor(maxc, 16));
    maxc = max(maxc, __shfl_xor(maxc, 8));

    const ushort* fp = y1b + l8 * 8;
    float s0 = 0.f, s1 = 0.f, s2 = 0.f, s3 = 0.f;
    float s4 = 0.f, s5 = 0.f, s6 = 0.f, s7 = 0.f;
    for (int k = 0; k < maxc; k += 8) {
        u16x8 vv[8];
        int nv = 0;
#pragma unroll
        for (int u = 0; u < 8; ++u) {
            int e = k + u;
            if (e < cnt) {
                int p = sl + e;
                int idx = (p < ECAP) ? (int)eidx[w][p] : (int)edge_src[gbase + p];
                vv[u] = *(const u16x8*)(fp + (size_t)idx * 64);
                nv = u + 1;
            }
        }
#pragma unroll
        for (int u = 0; u < 8; ++u) {
            if (u < nv) {
                s0 += bf2f(vv[u][0]); s1 += bf2f(vv[u][1]);
                s2 += bf2f(vv[u][2]); s3 += bf2f(vv[u][3]);
                s4 += bf2f(vv[u][4]); s5 += bf2f(vv[u][5]);
                s6 += bf2f(vv[u][6]); s7 += bf2f(vv[u][7]);
            }
        }
    }
    const int node = n0w + g;
    if (node < N_NODES) {
        float invd = 1.0f / fmaxf((float)cnt, 1.0f);
        float sv[8] = {s0, s1, s2, s3, s4, s5, s6, s7};
        const int c0 = l8 * 8;
#pragma unroll
        for (int j = 0; j < 8; ++j) {
            int c = c0 + j;
            if (c < N_CLASSES)
                out[(size_t)node * N_CLASSES + c] = sv[j] * invd + b2[c];
        }
    }
}

extern "C" void kernel_launch(void* const* d_in, const int* in_sizes, int n_in,
                              void* d_out, int out_size, void* d_ws, size_t ws_size,
                              hipStream_t stream) {
    const float* feat = (const float*)d_in[0];
    const int*   src  = (const int*)d_in[1];
    const int*   dst  = (const int*)d_in[2];
    const float* W1   = (const float*)d_in[3];
    const float* b1   = (const float*)d_in[4];
    const float* W2   = (const float*)d_in[5];
    const float* b2   = (const float*)d_in[6];
    float* out = (float*)d_out;

    char* ws = (char*)d_ws;
    int*           row_start = (int*)(ws + ROWS_OFF);
    int*           bsum      = (int*)(ws + BSUM_OFF);
    unsigned char* hist      = (unsigned char*)(ws + HIST_OFF);
    ushort*        edge_src  = (ushort*)(ws + ESRC_OFF);
    ushort*        y1b       = (ushort*)(ws + Y1B_OFF);
    unsigned char* feat8     = (unsigned char*)(ws + FEAT8_OFF);
    ushort*        w1p       = (ushort*)(ws + W1P_OFF);
    ushort*        w2p       = (ushort*)(ws + W2P_OFF);
    unsigned char* rank8     = (unsigned char*)d_out;   // 1.6 MB scratch in d_out

    k1_hist_conv<<<NBH + NCONV + 2, 512, 0, stream>>>(dst, hist, rank8, feat,
                                                      (unsigned int*)feat8,
                                                      W1, w1p, W2, w2p);
    k2_scan<<<K2B, 256, 0, stream>>>(hist, row_start, bsum);
    scan_c<<<(N_NODES + SB - 1) / SB, SB, 0, stream>>>(bsum, row_start);
    k4_fill<<<(N_EDGES + 255) / 256, 256, 0, stream>>>(src, dst, rank8, hist,
                                                       row_start, edge_src);

    agg0_mlp<<<N_NODES / NPB, 512, 0, stream>>>(feat8, row_start, edge_src,
                                                w1p, b1, w2p, y1b);

    gather1_all<<<NB_G1, 256, 0, stream>>>(y1b, row_start, edge_src, b2, out);
}